// Round 4
// baseline (121.433 us; speedup 1.0000x reference)
//
#include <hip/hip_runtime.h>
#include <hip/hip_bf16.h>
#include <stdint.h>

// ---------------------------------------------------------------------------
// FMICL loss on MI355X.
//   loss = -mean(s_pos) + 64 * ( sum_offdiag exp(-(2-2*G_ij)/2) / (N(N-1)) + 1e-8 )
//   G = Q @ Q^T, Q = fp8-e4m3(normalize(z1))  -- MX-scaled MFMA, unit scales.
//
// R3 changes vs R2:
//  - gram: dynamic work-stealing over the 528 triangle tiles with a 512-block
//    grid (2 blocks/CU). Fixes the 528-on-256-CU dispatch tail (makespan
//    3*t_tile -> ~2.1*t_tile). Work counter initialized by norm_spos
//    (kernel-boundary ordering), per-block star partial -> star[512].
//
// ws layout: [0, 4MB) fp8 Q ; float spos[4096] ; float star[512] ; int ctr
// ---------------------------------------------------------------------------

#define AS1 __attribute__((address_space(1)))
#define AS3 __attribute__((address_space(3)))

typedef unsigned short u16;
typedef uint8_t  u8;
typedef int    i32x4 __attribute__((ext_vector_type(4)));
typedef int    i32x8 __attribute__((ext_vector_type(8)));
typedef float  f32x4 __attribute__((ext_vector_type(4)));

constexpr int   D     = 1024;         // feature dim == GEMM K (bytes in fp8)
constexpr int   N     = 4096;         // rows per half
constexpr int   TM    = 128;          // tile M = tile N
constexpr int   BK    = 128;          // K-step per staging round (fp8 bytes)
constexpr int   NB    = N / TM;       // 32 tiles per side
constexpr int   NTRI  = NB * (NB + 1) / 2;  // 528 triangle tiles
constexpr int   GBLK  = 512;          // gram grid (2 blocks/CU)
constexpr float EPS   = 1e-8f;
constexpr float ALPHA = 64.0f;

__device__ __forceinline__ void async_load16(const void* g, void* l) {
    __builtin_amdgcn_global_load_lds((AS1 void*)g, (AS3 void*)l, 16, 0, 0);
}

// ---------------------------------------------------------------------------
// Kernel 1: per row-pair i: normalize z1_i, z2_i (fp32), store fp8 Q row,
// compute s_pos_i -> spos[i]. Block 0 also seeds gram's steal counter.
// ---------------------------------------------------------------------------
__global__ __launch_bounds__(256) void norm_spos_kernel(
    const float* __restrict__ z, u8* __restrict__ q, float* __restrict__ spos,
    int* __restrict__ ctr)
{
    const int row = blockIdx.x;   // 0..4095
    const int t   = threadIdx.x;  // 0..255
    const int lane = t & 63, wave = t >> 6;

    if (row == 0 && t == 0) *ctr = GBLK;   // next steal index

    const float4 a = ((const float4*)(z + (size_t)row       * D))[t];
    const float4 b = ((const float4*)(z + (size_t)(row + N) * D))[t];

    float s1 = a.x*a.x + a.y*a.y + a.z*a.z + a.w*a.w;
    float s2 = b.x*b.x + b.y*b.y + b.z*b.z + b.w*b.w;
    #pragma unroll
    for (int off = 32; off; off >>= 1) {
        s1 += __shfl_down(s1, off);
        s2 += __shfl_down(s2, off);
    }
    __shared__ float r1[4], r2[4], r3[4];
    if (lane == 0) { r1[wave] = s1; r2[wave] = s2; }
    __syncthreads();
    const float ss1 = r1[0] + r1[1] + r1[2] + r1[3];
    const float ss2 = r2[0] + r2[1] + r2[2] + r2[3];
    const float inv1 = 1.0f / fmaxf(sqrtf(ss1), 1e-12f);
    const float inv2 = 1.0f / fmaxf(sqrtf(ss2), 1e-12f);

    float4 an, bn;
    an.x = a.x * inv1; an.y = a.y * inv1; an.z = a.z * inv1; an.w = a.w * inv1;
    bn.x = b.x * inv2; bn.y = b.y * inv2; bn.z = b.z * inv2; bn.w = b.w * inv2;

    // pack 4 fp32 -> 4 fp8 e4m3 bytes (RNE, HW cvt)
    int u = __builtin_amdgcn_cvt_pk_fp8_f32(an.x, an.y, 0, false);
    u     = __builtin_amdgcn_cvt_pk_fp8_f32(an.z, an.w, u, true);
    ((int*)(q + (size_t)row * D))[t] = u;

    const float dx = an.x - bn.x, dy = an.y - bn.y, dz = an.z - bn.z, dw = an.w - bn.w;
    float dp = dx*dx + dy*dy + dz*dz + dw*dw;
    #pragma unroll
    for (int off = 32; off; off >>= 1) dp += __shfl_down(dp, off);
    if (lane == 0) r3[wave] = dp;
    __syncthreads();
    if (t == 0) {
        const float d_pos = r3[0] + r3[1] + r3[2] + r3[3];
        const float g     = expf(-0.5f * d_pos);
        spos[row] = logf(g + EPS) + 1.0f;
    }
}

// ---------------------------------------------------------------------------
// Kernel 2: fused Gram + exp-sum, work-stealing over the (bi<=bj) triangle.
// 256 threads = 4 waves, each wave a 64x64 sub-tile = 4x4 of 16x16x128 MX-fp8
// MFMA (unit scales). 8 K-iters of BK=128 per tile.
//
// LDS tiles [128 rows][128 B]: 16B granule g of row r stored at slot g^(r&7).
// global_load_lds dest stays linear in lane order (constraint); only the
// global SOURCE granule is permuted. Fragment = two b128 halves per lane.
// ---------------------------------------------------------------------------
__global__ __launch_bounds__(256) void gram_kernel(
    const u8* __restrict__ Q, float* __restrict__ star_part, int* __restrict__ ctr)
{
    __shared__ __align__(16) u8 lA[TM * BK];  // 16 KB
    __shared__ __align__(16) u8 lB[TM * BK];  // 16 KB
    __shared__ float wsum[4];
    __shared__ int   nxt;

    const int t    = threadIdx.x;
    const int lane = t & 63;
    const int wave = t >> 6;
    const int wm   = (wave & 1) * 64;
    const int wn   = (wave >> 1) * 64;
    const int fr   = lane & 15;        // fragment row (m or n)
    const int fq   = lane >> 4;        // k-quad 0..3 (32 B each)

    // staging geometry: 1024 16B-granules per tile, thread handles p = t+256*j
    int   ro[4], co[4];                // row, swizzled-column per chunk
    #pragma unroll
    for (int j = 0; j < 4; ++j) {
        const int p = t + 256 * j;
        ro[j] = p >> 3;
        co[j] = ((p & 7) ^ (ro[j] & 7)) * 16;   // XOR swizzle (self-inverse)
    }

    float bsum = 0.0f;   // per-lane running star partial (weighted)

    for (int tile = blockIdx.x; tile < NTRI; ) {
        // triangle decode: tile -> (bi, bj), bi <= bj
        int bi = 0, rem = tile;
        while (rem >= NB - bi) { rem -= NB - bi; ++bi; }
        const int bj    = bi + rem;
        const int rowA0 = bi * TM, rowB0 = bj * TM;
        const bool diag = (bi == bj);
        const u8* QA = Q + (size_t)rowA0 * D;
        const u8* QB = Q + (size_t)rowB0 * D;

        f32x4 acc[4][4];
        #pragma unroll
        for (int mt = 0; mt < 4; ++mt)
            #pragma unroll
            for (int nt = 0; nt < 4; ++nt)
                acc[mt][nt] = f32x4{0.f, 0.f, 0.f, 0.f};

        for (int k0 = 0; k0 < D; k0 += BK) {
            #pragma unroll
            for (int j = 0; j < 4; ++j) {
                const size_t go = (size_t)ro[j] * D + k0 + co[j];
                async_load16(QA + go, &lA[(t + 256 * j) * 16]);
                async_load16(QB + go, &lB[(t + 256 * j) * 16]);
            }
            __syncthreads();   // drains vmcnt for the LDS-DMA

            i32x8 af[4], bf[4];
            #pragma unroll
            for (int mt = 0; mt < 4; ++mt) {
                const int r = wm + mt * 16 + fr;
                const i32x4* base = (const i32x4*)&lA[r * BK];
                const i32x4 lo = base[(2 * fq    ) ^ (r & 7)];
                const i32x4 hi = base[(2 * fq + 1) ^ (r & 7)];
                af[mt][0] = lo[0]; af[mt][1] = lo[1]; af[mt][2] = lo[2]; af[mt][3] = lo[3];
                af[mt][4] = hi[0]; af[mt][5] = hi[1]; af[mt][6] = hi[2]; af[mt][7] = hi[3];
            }
            #pragma unroll
            for (int nt = 0; nt < 4; ++nt) {
                const int r = wn + nt * 16 + fr;
                const i32x4* base = (const i32x4*)&lB[r * BK];
                const i32x4 lo = base[(2 * fq    ) ^ (r & 7)];
                const i32x4 hi = base[(2 * fq + 1) ^ (r & 7)];
                bf[nt][0] = lo[0]; bf[nt][1] = lo[1]; bf[nt][2] = lo[2]; bf[nt][3] = lo[3];
                bf[nt][4] = hi[0]; bf[nt][5] = hi[1]; bf[nt][6] = hi[2]; bf[nt][7] = hi[3];
            }

            #pragma unroll
            for (int mt = 0; mt < 4; ++mt)
                #pragma unroll
                for (int nt = 0; nt < 4; ++nt)
                    acc[mt][nt] = __builtin_amdgcn_mfma_scale_f32_16x16x128_f8f6f4(
                        af[mt], bf[nt], acc[mt][nt],
                        0, 0,               // cbsz=fp8, blgp=fp8
                        0, 0x7f7f7f7f,      // scale A: e8m0 127 = 1.0
                        0, 0x7f7f7f7f);     // scale B

            __syncthreads();   // protect LDS before next staging round
        }

        // Epilogue (regs only): e = exp(-max(2-2g,0)/2); diag masks i==j.
        const float w = diag ? 1.0f : 2.0f;
        float tsum = 0.0f;
        #pragma unroll
        for (int mt = 0; mt < 4; ++mt) {
            #pragma unroll
            for (int nt = 0; nt < 4; ++nt) {
                #pragma unroll
                for (int r = 0; r < 4; ++r) {
                    const float g  = acc[mt][nt][r];
                    const int   gi = wm + mt * 16 + fq * 4 + r;   // local row
                    const int   gj = wn + nt * 16 + fr;           // local col
                    const float d2 = fmaxf(2.0f - 2.0f * g, 0.0f);
                    const float e  = __expf(-0.5f * d2);
                    tsum += (diag && gi == gj) ? 0.0f : e;
                }
            }
        }
        bsum += w * tsum;

        // steal next tile
        if (t == 0) nxt = atomicAdd(ctr, 1);
        __syncthreads();
        tile = nxt;
    }

    // block reduction of bsum -> star_part[blockIdx.x]
    #pragma unroll
    for (int off = 32; off; off >>= 1) bsum += __shfl_down(bsum, off);
    if (lane == 0) wsum[wave] = bsum;
    __syncthreads();
    if (t == 0)
        star_part[blockIdx.x] = wsum[0] + wsum[1] + wsum[2] + wsum[3];
}

// ---------------------------------------------------------------------------
// Kernel 3: sum the partials, assemble the scalar loss.
// ---------------------------------------------------------------------------
__global__ __launch_bounds__(256) void finalize_kernel(
    const float* __restrict__ spos, const float* __restrict__ star,
    float* __restrict__ out)
{
    const int t = threadIdx.x, lane = t & 63, wave = t >> 6;
    float s1 = 0.0f, s2 = 0.0f;
    for (int i = t; i < N;    i += 256) s1 += spos[i];
    for (int i = t; i < GBLK; i += 256) s2 += star[i];
    #pragma unroll
    for (int off = 32; off; off >>= 1) {
        s1 += __shfl_down(s1, off);
        s2 += __shfl_down(s2, off);
    }
    __shared__ float r1[4], r2[4];
    if (lane == 0) { r1[wave] = s1; r2[wave] = s2; }
    __syncthreads();
    if (t == 0) {
        const float spos_sum = r1[0] + r1[1] + r1[2] + r1[3];
        const float star_sum = r2[0] + r2[1] + r2[2] + r2[3];
        const float star_mean = star_sum / ((float)N * (float)(N - 1)) + EPS;
        out[0] = -spos_sum / (float)N + ALPHA * star_mean;
    }
}

// ---------------------------------------------------------------------------
extern "C" void kernel_launch(void* const* d_in, const int* in_sizes, int n_in,
                              void* d_out, int out_size, void* d_ws, size_t ws_size,
                              hipStream_t stream)
{
    (void)in_sizes; (void)n_in; (void)out_size; (void)ws_size;
    const float* z    = (const float*)d_in[0];
    float*       out  = (float*)d_out;
    u8*          q    = (u8*)d_ws;                                   // 4 MB fp8
    float*       spos = (float*)((char*)d_ws + (size_t)N * D);       // 4096 f
    float*       star = spos + N;                                    // 512 f
    int*         ctr  = (int*)(star + GBLK);                         // 1 int

    hipLaunchKernelGGL(norm_spos_kernel, dim3(N),    dim3(256), 0, stream, z, q, spos, ctr);
    hipLaunchKernelGGL(gram_kernel,      dim3(GBLK), dim3(256), 0, stream, q, star, ctr);
    hipLaunchKernelGGL(finalize_kernel,  dim3(1),    dim3(256), 0, stream, spos, star, out);
}

// Round 5
// 92.852 us; speedup vs baseline: 1.3078x; 1.3078x over previous
//
#include <hip/hip_runtime.h>
#include <hip/hip_bf16.h>
#include <stdint.h>

// ---------------------------------------------------------------------------
// FMICL loss on MI355X.
//   loss = -mean(s_pos) + 64 * ( sum_offdiag exp(-(2-2*G_ij)/2) / (N(N-1)) + 1e-8 )
//   G = Q @ Q^T, Q = fp8-e4m3(normalize(z1))  -- MX-scaled MFMA, unit scales.
//
// R5 changes vs R4:
//  - REVERT work-stealing (VGPR 256 -> occupancy collapse, gram 45us).
//    Static triangle grid (528 blocks) as in R3.
//  - gram fragment loop restructured for register pressure: bf[4] preloaded
//    per k-iter, af loaded one mt at a time. Live set ~110 regs vs 256.
//  - __launch_bounds__(256, 3): pin >=3 waves/EU (3 blocks/CU, LDS 33KB x3).
//
// ws layout: [0, 4MB) fp8 Q ; float spos[4096] ; float star[528]
// ---------------------------------------------------------------------------

#define AS1 __attribute__((address_space(1)))
#define AS3 __attribute__((address_space(3)))

typedef unsigned short u16;
typedef uint8_t  u8;
typedef int    i32x4 __attribute__((ext_vector_type(4)));
typedef int    i32x8 __attribute__((ext_vector_type(8)));
typedef float  f32x4 __attribute__((ext_vector_type(4)));

constexpr int   D     = 1024;         // feature dim == GEMM K (bytes in fp8)
constexpr int   N     = 4096;         // rows per half
constexpr int   TM    = 128;          // tile M = tile N
constexpr int   BK    = 128;          // K-step per staging round (fp8 bytes)
constexpr int   NB    = N / TM;       // 32 tiles per side
constexpr int   NTRI  = NB * (NB + 1) / 2;  // 528 triangle tiles
constexpr float EPS   = 1e-8f;
constexpr float ALPHA = 64.0f;

__device__ __forceinline__ void async_load16(const void* g, void* l) {
    __builtin_amdgcn_global_load_lds((AS1 void*)g, (AS3 void*)l, 16, 0, 0);
}

// ---------------------------------------------------------------------------
// Kernel 1: per row-pair i: normalize z1_i, z2_i (fp32), store fp8 Q row,
// compute s_pos_i -> spos[i].
// ---------------------------------------------------------------------------
__global__ __launch_bounds__(256) void norm_spos_kernel(
    const float* __restrict__ z, u8* __restrict__ q, float* __restrict__ spos)
{
    const int row = blockIdx.x;   // 0..4095
    const int t   = threadIdx.x;  // 0..255
    const int lane = t & 63, wave = t >> 6;

    const float4 a = ((const float4*)(z + (size_t)row       * D))[t];
    const float4 b = ((const float4*)(z + (size_t)(row + N) * D))[t];

    float s1 = a.x*a.x + a.y*a.y + a.z*a.z + a.w*a.w;
    float s2 = b.x*b.x + b.y*b.y + b.z*b.z + b.w*b.w;
    #pragma unroll
    for (int off = 32; off; off >>= 1) {
        s1 += __shfl_down(s1, off);
        s2 += __shfl_down(s2, off);
    }
    __shared__ float r1[4], r2[4], r3[4];
    if (lane == 0) { r1[wave] = s1; r2[wave] = s2; }
    __syncthreads();
    const float ss1 = r1[0] + r1[1] + r1[2] + r1[3];
    const float ss2 = r2[0] + r2[1] + r2[2] + r2[3];
    const float inv1 = 1.0f / fmaxf(sqrtf(ss1), 1e-12f);
    const float inv2 = 1.0f / fmaxf(sqrtf(ss2), 1e-12f);

    float4 an, bn;
    an.x = a.x * inv1; an.y = a.y * inv1; an.z = a.z * inv1; an.w = a.w * inv1;
    bn.x = b.x * inv2; bn.y = b.y * inv2; bn.z = b.z * inv2; bn.w = b.w * inv2;

    // pack 4 fp32 -> 4 fp8 e4m3 bytes (RNE, HW cvt)
    int u = __builtin_amdgcn_cvt_pk_fp8_f32(an.x, an.y, 0, false);
    u     = __builtin_amdgcn_cvt_pk_fp8_f32(an.z, an.w, u, true);
    ((int*)(q + (size_t)row * D))[t] = u;

    const float dx = an.x - bn.x, dy = an.y - bn.y, dz = an.z - bn.z, dw = an.w - bn.w;
    float dp = dx*dx + dy*dy + dz*dz + dw*dw;
    #pragma unroll
    for (int off = 32; off; off >>= 1) dp += __shfl_down(dp, off);
    if (lane == 0) r3[wave] = dp;
    __syncthreads();
    if (t == 0) {
        const float d_pos = r3[0] + r3[1] + r3[2] + r3[3];
        const float g     = expf(-0.5f * d_pos);
        spos[row] = logf(g + EPS) + 1.0f;
    }
}

// ---------------------------------------------------------------------------
// Kernel 2: fused Gram + exp-sum over the (bi<=bj) triangle of 128x128 tiles.
// 256 threads = 4 waves, each wave a 64x64 sub-tile = 4x4 of 16x16x128 MX-fp8
// MFMA (unit scales). 8 K-iters of BK=128.
//
// LDS tiles [128 rows][128 B]: 16B granule g of row r stored at slot g^(r&7).
// global_load_lds dest stays linear in lane order (constraint); only the
// global SOURCE granule is permuted. Fragment = two b128 halves per lane.
// Register budget: bf[4]=32 + af=8 + acc=64 -> ~110 live; bounds (256,3).
// ---------------------------------------------------------------------------
__global__ __launch_bounds__(256, 3) void gram_kernel(
    const u8* __restrict__ Q, float* __restrict__ star_part)
{
    __shared__ __align__(16) u8 lA[TM * BK];  // 16 KB
    __shared__ __align__(16) u8 lB[TM * BK];  // 16 KB
    __shared__ float wsum[4];

    // triangle decode: blockIdx.x -> (bi, bj), bi <= bj
    int bi = 0, rem = blockIdx.x;
    while (rem >= NB - bi) { rem -= NB - bi; ++bi; }
    const int bj    = bi + rem;
    const int rowA0 = bi * TM, rowB0 = bj * TM;
    const bool diag = (bi == bj);

    const int t    = threadIdx.x;
    const int lane = t & 63;
    const int wave = t >> 6;
    const int wm   = (wave & 1) * 64;
    const int wn   = (wave >> 1) * 64;
    const int fr   = lane & 15;        // fragment row (m or n)
    const int fq   = lane >> 4;        // k-quad 0..3 (32 B each)

    // staging: 1024 16B-granules per tile, thread handles p = t + 256*j
    const u8* gA[4]; const u8* gB[4]; u8* dA[4]; u8* dB[4];
    #pragma unroll
    for (int j = 0; j < 4; ++j) {
        const int p = t + 256 * j;
        const int r = p >> 3;
        const int c = (p & 7) ^ (r & 7);   // XOR swizzle (self-inverse)
        gA[j] = Q + (size_t)(rowA0 + r) * D + c * 16;
        gB[j] = Q + (size_t)(rowB0 + r) * D + c * 16;
        dA[j] = &lA[p * 16];
        dB[j] = &lB[p * 16];
    }

    f32x4 acc[4][4];
    #pragma unroll
    for (int mt = 0; mt < 4; ++mt)
        #pragma unroll
        for (int nt = 0; nt < 4; ++nt)
            acc[mt][nt] = f32x4{0.f, 0.f, 0.f, 0.f};

    for (int k0 = 0; k0 < D; k0 += BK) {
        #pragma unroll
        for (int j = 0; j < 4; ++j) {
            async_load16(gA[j] + k0, dA[j]);
            async_load16(gB[j] + k0, dB[j]);
        }
        __syncthreads();   // drains vmcnt for the LDS-DMA

        // preload all B fragments (32 regs live), then stream A one mt at a time
        i32x8 bf[4];
        #pragma unroll
        for (int nt = 0; nt < 4; ++nt) {
            const int r = wn + nt * 16 + fr;
            const i32x4* base = (const i32x4*)&lB[r * BK];
            const i32x4 lo = base[(2 * fq    ) ^ (r & 7)];
            const i32x4 hi = base[(2 * fq + 1) ^ (r & 7)];
            bf[nt][0] = lo[0]; bf[nt][1] = lo[1]; bf[nt][2] = lo[2]; bf[nt][3] = lo[3];
            bf[nt][4] = hi[0]; bf[nt][5] = hi[1]; bf[nt][6] = hi[2]; bf[nt][7] = hi[3];
        }
        #pragma unroll
        for (int mt = 0; mt < 4; ++mt) {
            const int r = wm + mt * 16 + fr;
            const i32x4* base = (const i32x4*)&lA[r * BK];
            const i32x4 lo = base[(2 * fq    ) ^ (r & 7)];
            const i32x4 hi = base[(2 * fq + 1) ^ (r & 7)];
            i32x8 af;
            af[0] = lo[0]; af[1] = lo[1]; af[2] = lo[2]; af[3] = lo[3];
            af[4] = hi[0]; af[5] = hi[1]; af[6] = hi[2]; af[7] = hi[3];
            #pragma unroll
            for (int nt = 0; nt < 4; ++nt)
                acc[mt][nt] = __builtin_amdgcn_mfma_scale_f32_16x16x128_f8f6f4(
                    af, bf[nt], acc[mt][nt],
                    0, 0,               // cbsz=fp8, blgp=fp8
                    0, 0x7f7f7f7f,      // scale A: e8m0 127 = 1.0
                    0, 0x7f7f7f7f);     // scale B
        }

        __syncthreads();   // protect LDS before next staging round
    }

    // Epilogue: e = exp(-max(2-2g,0)/2); diag tile masks i==j; off-diag x2.
    float lsum = 0.0f;
    #pragma unroll
    for (int mt = 0; mt < 4; ++mt) {
        #pragma unroll
        for (int nt = 0; nt < 4; ++nt) {
            #pragma unroll
            for (int r = 0; r < 4; ++r) {
                const float g  = acc[mt][nt][r];
                const int   gi = wm + mt * 16 + fq * 4 + r;   // local row
                const int   gj = wn + nt * 16 + fr;           // local col
                const float d2 = fmaxf(2.0f - 2.0f * g, 0.0f);
                const float e  = __expf(-0.5f * d2);
                lsum += (diag && gi == gj) ? 0.0f : e;
            }
        }
    }
    #pragma unroll
    for (int off = 32; off; off >>= 1) lsum += __shfl_down(lsum, off);
    if (lane == 0) wsum[wave] = lsum;
    __syncthreads();
    if (t == 0)
        star_part[blockIdx.x] = (diag ? 1.0f : 2.0f) *
                                (wsum[0] + wsum[1] + wsum[2] + wsum[3]);
}

// ---------------------------------------------------------------------------
// Kernel 3: sum the partials, assemble the scalar loss.
// ---------------------------------------------------------------------------
__global__ __launch_bounds__(256) void finalize_kernel(
    const float* __restrict__ spos, const float* __restrict__ star,
    float* __restrict__ out)
{
    const int t = threadIdx.x, lane = t & 63, wave = t >> 6;
    float s1 = 0.0f, s2 = 0.0f;
    for (int i = t; i < N;    i += 256) s1 += spos[i];
    for (int i = t; i < NTRI; i += 256) s2 += star[i];
    #pragma unroll
    for (int off = 32; off; off >>= 1) {
        s1 += __shfl_down(s1, off);
        s2 += __shfl_down(s2, off);
    }
    __shared__ float r1[4], r2[4];
    if (lane == 0) { r1[wave] = s1; r2[wave] = s2; }
    __syncthreads();
    if (t == 0) {
        const float spos_sum = r1[0] + r1[1] + r1[2] + r1[3];
        const float star_sum = r2[0] + r2[1] + r2[2] + r2[3];
        const float star_mean = star_sum / ((float)N * (float)(N - 1)) + EPS;
        out[0] = -spos_sum / (float)N + ALPHA * star_mean;
    }
}

// ---------------------------------------------------------------------------
extern "C" void kernel_launch(void* const* d_in, const int* in_sizes, int n_in,
                              void* d_out, int out_size, void* d_ws, size_t ws_size,
                              hipStream_t stream)
{
    (void)in_sizes; (void)n_in; (void)out_size; (void)ws_size;
    const float* z    = (const float*)d_in[0];
    float*       out  = (float*)d_out;
    u8*          q    = (u8*)d_ws;                                   // 4 MB fp8
    float*       spos = (float*)((char*)d_ws + (size_t)N * D);       // 4096 f
    float*       star = spos + N;                                    // 528 f

    hipLaunchKernelGGL(norm_spos_kernel, dim3(N),    dim3(256), 0, stream, z, q, spos);
    hipLaunchKernelGGL(gram_kernel,      dim3(NTRI), dim3(256), 0, stream, q, star);
    hipLaunchKernelGGL(finalize_kernel,  dim3(1),    dim3(256), 0, stream, spos, star, out);
}